// Round 9
// baseline (205.635 us; speedup 1.0000x reference)
//
#include <hip/hip_runtime.h>
#include <hip/hip_bf16.h>

#define S_LEN 2048
#define EMB_D 1024
#define NH 16
#define DK 64
#define BATCH 4

typedef __attribute__((ext_vector_type(8))) short short8;
typedef __attribute__((ext_vector_type(4))) float f32x4;
typedef __attribute__((ext_vector_type(8))) unsigned short ushort8;
typedef __attribute__((ext_vector_type(4))) unsigned short ushort4v;
typedef __attribute__((ext_vector_type(4))) unsigned int uint4v;
typedef __attribute__((ext_vector_type(2))) unsigned int uint2v;

__device__ inline unsigned short f2bf(float x) {
    unsigned u = __builtin_bit_cast(unsigned, x);
    u = (u + 0x7fffu + ((u >> 16) & 1u)) >> 16;
    return (unsigned short)u;
}

__device__ inline unsigned cvtpk(float lo, float hi) {
    unsigned r;
    asm("v_cvt_pk_bf16_f32 %0, %1, %2" : "=v"(r) : "v"(lo), "v"(hi));
    return r;
}

typedef const __attribute__((address_space(1))) unsigned int* gas_p;
typedef __attribute__((address_space(3))) unsigned int* las_p;
__device__ inline void gload16(const void* g, void* l) {
    __builtin_amdgcn_global_load_lds((gas_p)g, (las_p)l, 16, 0, 0);
}

// ---- fused f32 -> bf16 conversion over up to 7 tensors ----
struct CvtArgs {
    const float* src[7];
    unsigned short* dst[7];
    int starts[8];
    int ntens;
};

__global__ __launch_bounds__(256) void cvt_all(CvtArgs a) {
    int b = blockIdx.x;
    int t = 0;
#pragma unroll
    for (int i = 1; i < 7; ++i)
        if (i < a.ntens && b >= a.starts[i]) t = i;
    int rel = b - a.starts[t];
    size_t i = (size_t)rel * 2048 + (size_t)threadIdx.x * 8;
    float4 x = *(const float4*)&a.src[t][i];
    float4 y = *(const float4*)&a.src[t][i + 4];
    uint4v w;
    w.x = cvtpk(x.x, x.y); w.y = cvtpk(x.z, x.w);
    w.z = cvtpk(y.x, y.y); w.w = cvtpk(y.z, y.w);
    *(uint4v*)&a.dst[t][i] = w;
}

// ======== BK=32 triple-buffered counted-vmcnt GEMM core (T3/T4-minimum) ========
// LDS rows are 64B. Staging swizzle: source granule = (lane&3)^((lane>>3)&3);
// fragment read slot = l4 ^ ((l15>>1)&3)  ->  2-way max bank aliasing (free).
// Stage-ahead-2: iter kt issues tile kt+2; end-of-iter s_waitcnt vmcnt(4) leaves
// tile kt+2's 4 loads in flight while guaranteeing tile kt+1 landed.

#define GEMM32_LOOP(AB_EXPR, BW_EXPR)                                              \
    auto stage = [&](int s, int kt) {                                              \
        _Pragma("unroll")                                                          \
        for (int j2 = 0; j2 < 2; ++j2) {                                           \
            int rb = j2 * 64 + w16;                                                \
            gload16(AB_EXPR, &As[s][rb][0]);                                       \
        }                                                                          \
        _Pragma("unroll")                                                          \
        for (int j2 = 0; j2 < 2; ++j2) {                                           \
            int rb = j2 * 64 + w16;                                                \
            gload16(BW_EXPR, &Bs[s][rb][0]);                                       \
        }                                                                          \
    };                                                                             \
    stage(0, 0);                                                                   \
    stage(1, 1);                                                                   \
    asm volatile("s_waitcnt vmcnt(4)" ::: "memory");                               \
    __builtin_amdgcn_sched_barrier(0);                                             \
    __builtin_amdgcn_s_barrier();                                                  \
    __builtin_amdgcn_sched_barrier(0);                                             \
    for (int kt = 0; kt < 32; ++kt) {                                              \
        const int scur = kt % 3;                                                   \
        if (kt + 2 < 32) stage((kt + 2) % 3, kt + 2);                              \
        __builtin_amdgcn_sched_barrier(0);                                         \
        short8 af[4], bf[4];                                                       \
        _Pragma("unroll")                                                          \
        for (int m = 0; m < 4; ++m)                                                \
            af[m] = *(const short8*)&As[scur][wr * 64 + m * 16 + l15][fsl];        \
        _Pragma("unroll")                                                          \
        for (int n = 0; n < 4; ++n)                                                \
            bf[n] = *(const short8*)&Bs[scur][wc * 64 + n * 16 + l15][fsl];        \
        _Pragma("unroll")                                                          \
        for (int m = 0; m < 4; ++m)                                                \
            _Pragma("unroll")                                                      \
            for (int n = 0; n < 4; ++n)                                            \
                acc[m][n] = __builtin_amdgcn_mfma_f32_16x16x32_bf16(               \
                    af[m], bf[n], acc[m][n], 0, 0, 0);                             \
        if (kt + 2 < 32) { asm volatile("s_waitcnt vmcnt(4)" ::: "memory"); }      \
        else             { asm volatile("s_waitcnt vmcnt(0)" ::: "memory"); }      \
        __builtin_amdgcn_sched_barrier(0);                                         \
        __builtin_amdgcn_s_barrier();                                              \
        __builtin_amdgcn_sched_barrier(0);                                         \
    }

// ---- fused QKV projection, BK=32 counted-vmcnt ----
__global__ __launch_bounds__(256) void gemm_qkv32(
    const unsigned short* __restrict__ Aq, const unsigned short* __restrict__ Ak,
    const unsigned short* __restrict__ Av, const unsigned short* __restrict__ Wcat,
    const float* __restrict__ bq, const float* __restrict__ bk, const float* __restrict__ bv,
    unsigned short* __restrict__ Qh, unsigned short* __restrict__ Kh,
    unsigned short* __restrict__ Vt, float qscale)
{
    const int K = EMB_D;
    __shared__ unsigned short As[3][128][32];   // 24 KB
    __shared__ unsigned short Bs[3][128][32];   // 24 KB

    const int tid = threadIdx.x;
    const int lane = tid & 63;
    const int wid = tid >> 6;
    const int wr = wid >> 1, wc = wid & 1;
    const int l15 = lane & 15, l4 = lane >> 4;

    const int bid = blockIdx.x;
    const int xcd = bid & 7, j = bid >> 3;
    const int tau = j >> 6, jj = j & 63;
    const int bnl = jj & 7;
    const int bm = xcd * 8 + (jj >> 3);

    const unsigned short* Ab = tau == 0 ? Aq : (tau == 1 ? Ak : Av);
    const unsigned short* Bw = Wcat + (size_t)tau * (size_t)EMB_D * EMB_D;
    const float* bias = tau == 0 ? bq : (tau == 1 ? bk : bv);
    const float osc = tau == 0 ? qscale : 1.0f;

    const int srow4 = lane >> 2;
    const int sgl4 = ((lane & 3) ^ ((lane >> 3) & 3)) * 8;   // element offset
    const int w16 = wid * 16;
    const int fsl = (l4 ^ ((l15 >> 1) & 3)) * 8;

    f32x4 acc[4][4];
#pragma unroll
    for (int m = 0; m < 4; ++m)
#pragma unroll
        for (int n = 0; n < 4; ++n) {
            f32x4 z = {0.f, 0.f, 0.f, 0.f};
            acc[m][n] = z;
        }

    GEMM32_LOOP(
        &Ab[(size_t)(bm * 128 + rb + srow4) * K + kt * 32 + sgl4],
        &Bw[(size_t)(bnl * 128 + rb + srow4) * K + kt * 32 + sgl4])

#pragma unroll
    for (int m = 0; m < 4; ++m) {
#pragma unroll
        for (int n = 0; n < 4; ++n) {
            int gm0 = bm * 128 + wr * 64 + m * 16 + l4 * 4;
            int gn = bnl * 128 + wc * 64 + n * 16 + l15;
            if (tau == 2) {
                int b = gm0 >> 11, s0 = gm0 & 2047;
                int h = gn >> 6, d = gn & 63;
                ushort4v w;
#pragma unroll
                for (int r = 0; r < 4; ++r)
                    w[r] = f2bf(acc[m][n][r] + bias[gn]);
                *(ushort4v*)&Vt[((size_t)(b * NH + h) * DK + d) * S_LEN + s0] = w;
            } else {
                unsigned short* Out = tau == 0 ? Qh : Kh;
#pragma unroll
                for (int r = 0; r < 4; ++r) {
                    int gm = gm0 + r;
                    float val = (acc[m][n][r] + bias[gn]) * osc;
                    int b = gm >> 11, s = gm & 2047;
                    int h = gn >> 6, d = gn & 63;
                    Out[((size_t)(b * NH + h) * S_LEN + s) * DK + d] = f2bf(val);
                }
            }
        }
    }
}

// ---- final output projection: A bf16 [8192,1024] @ W^T + bias -> f32, BK=32 counted-vmcnt ----
__global__ __launch_bounds__(256) void gemm32_f32out(
    const unsigned short* __restrict__ Ain, const unsigned short* __restrict__ Bwp,
    const float* __restrict__ bias, float* __restrict__ Cout)
{
    const int K = EMB_D;
    __shared__ unsigned short As[3][128][32];
    __shared__ unsigned short Bs[3][128][32];

    const int tid = threadIdx.x;
    const int lane = tid & 63;
    const int wid = tid >> 6;
    const int wr = wid >> 1, wc = wid & 1;
    const int l15 = lane & 15, l4 = lane >> 4;

    const int bid = blockIdx.x;
    const int bm = (bid & 7) * 8 + (bid >> 6);
    const int bn = (bid >> 3) & 7;

    const unsigned short* Ab = Ain;
    const unsigned short* Bw = Bwp;

    const int srow4 = lane >> 2;
    const int sgl4 = ((lane & 3) ^ ((lane >> 3) & 3)) * 8;
    const int w16 = wid * 16;
    const int fsl = (l4 ^ ((l15 >> 1) & 3)) * 8;

    f32x4 acc[4][4];
#pragma unroll
    for (int m = 0; m < 4; ++m)
#pragma unroll
        for (int n = 0; n < 4; ++n) {
            f32x4 z = {0.f, 0.f, 0.f, 0.f};
            acc[m][n] = z;
        }

    GEMM32_LOOP(
        &Ab[(size_t)(bm * 128 + rb + srow4) * K + kt * 32 + sgl4],
        &Bw[(size_t)(bn * 128 + rb + srow4) * K + kt * 32 + sgl4])

#pragma unroll
    for (int m = 0; m < 4; ++m) {
#pragma unroll
        for (int n = 0; n < 4; ++n) {
            int gm0 = bm * 128 + wr * 64 + m * 16 + l4 * 4;
            int gn = bn * 128 + wc * 64 + n * 16 + l15;
#pragma unroll
            for (int r = 0; r < 4; ++r)
                Cout[(size_t)(gm0 + r) * EMB_D + gn] = acc[m][n][r] + bias[gn];
        }
    }
}

// ---- legacy BK=64 dbuf GEMM (fallback path only, round-8 proven) ----
template<int A_MODE, int OUT_MODE>
__global__ __launch_bounds__(256) void gemm_bt(
    const void* __restrict__ Aptr, const unsigned short* __restrict__ Bw,
    const float* __restrict__ bias, void* __restrict__ Cout, float oscale)
{
    const int K = EMB_D;
    __shared__ unsigned short As[2][128][64];
    __shared__ unsigned short Bs[2][128][64];

    const int tid = threadIdx.x;
    const int lane = tid & 63;
    const int wid = tid >> 6;
    const int wr = wid >> 1, wc = wid & 1;
    const int l15 = lane & 15, l4 = lane >> 4;
    const int lx7 = l15 & 7;

    const int bid = blockIdx.x;
    const int bm = (bid & 7) * 8 + (bid >> 6);
    const int bn = (bid >> 3) & 7;

    const int srow = lane >> 3;
    const int sgl = lane & 7;

    const float* Af = (const float*)Aptr;
    const unsigned short* Ab = (const unsigned short*)Aptr;

    f32x4 acc[4][4];
#pragma unroll
    for (int m = 0; m < 4; ++m)
#pragma unroll
        for (int n = 0; n < 4; ++n) {
            f32x4 z = {0.f, 0.f, 0.f, 0.f};
            acc[m][n] = z;
        }

    float4 areg[8];

    auto stageB = [&](int c, int kt) {
#pragma unroll
        for (int q2 = 0; q2 < 4; ++q2) {
            int r = wid * 32 + q2 * 8 + srow;
            gload16(&Bw[(size_t)(bn * 128 + r) * K + kt * 64 + (sgl ^ srow) * 8],
                    &Bs[c][wid * 32 + q2 * 8][0]);
        }
    };
    auto stageA1 = [&](int c, int kt) {
#pragma unroll
        for (int q2 = 0; q2 < 4; ++q2) {
            int r = wid * 32 + q2 * 8 + srow;
            gload16(&Ab[(size_t)(bm * 128 + r) * K + kt * 64 + (sgl ^ srow) * 8],
                    &As[c][wid * 32 + q2 * 8][0]);
        }
    };
    auto loadA0 = [&](int kt) {
#pragma unroll
        for (int j = 0; j < 8; ++j) {
            int f = tid + j * 256;
            int r = f >> 4, c4 = f & 15;
            areg[j] = *(const float4*)&Af[(size_t)(bm * 128 + r) * K + kt * 64 + c4 * 4];
        }
    };
    auto writeA0 = [&](int c) {
#pragma unroll
        for (int j = 0; j < 8; ++j) {
            int f = tid + j * 256;
            int r = f >> 4, c4 = f & 15;
            uint2v w;
            w.x = cvtpk(areg[j].x, areg[j].y);
            w.y = cvtpk(areg[j].z, areg[j].w);
            int col = (((c4 >> 1) ^ (r & 7)) << 3) + ((c4 & 1) << 2);
            *(uint2v*)&As[c][r][col] = w;
        }
    };

    if (A_MODE == 0) loadA0(0); else stageA1(0, 0);
    stageB(0, 0);
    if (A_MODE == 0) {
        asm volatile("s_waitcnt vmcnt(0)" ::: "memory");
        writeA0(0);
    }
    __syncthreads();

    for (int kt = 0; kt < K / 64; ++kt) {
        const int c = kt & 1;
        const bool pf = (kt + 1 < K / 64);
        if (pf) {
            if (A_MODE == 0) loadA0(kt + 1); else stageA1(c ^ 1, kt + 1);
            stageB(c ^ 1, kt + 1);
        }
#pragma unroll
        for (int h = 0; h < 2; ++h) {
            short8 af[4], bf[4];
#pragma unroll
            for (int m = 0; m < 4; ++m)
                af[m] = *(const short8*)&As[c][wr * 64 + m * 16 + l15][((h * 4 + l4) ^ lx7) * 8];
#pragma unroll
            for (int n = 0; n < 4; ++n)
                bf[n] = *(const short8*)&Bs[c][wc * 64 + n * 16 + l15][((h * 4 + l4) ^ lx7) * 8];
#pragma unroll
            for (int m = 0; m < 4; ++m)
#pragma unroll
                for (int n = 0; n < 4; ++n)
                    acc[m][n] = __builtin_amdgcn_mfma_f32_16x16x32_bf16(af[m], bf[n], acc[m][n], 0, 0, 0);
        }
        if (pf && A_MODE == 0) {
            asm volatile("s_waitcnt vmcnt(0)" ::: "memory");
            writeA0(c ^ 1);
        }
        __syncthreads();
    }

#pragma unroll
    for (int m = 0; m < 4; ++m) {
#pragma unroll
        for (int n = 0; n < 4; ++n) {
            int gm0 = bm * 128 + wr * 64 + m * 16 + l4 * 4;
            int gn = bn * 128 + wc * 64 + n * 16 + l15;
            if (OUT_MODE == 2) {
                int b = gm0 >> 11, s0 = gm0 & 2047;
                int h = gn >> 6, d = gn & 63;
                ushort4v w;
#pragma unroll
                for (int r = 0; r < 4; ++r)
                    w[r] = f2bf((acc[m][n][r] + bias[gn]) * oscale);
                *(ushort4v*)&((unsigned short*)Cout)[((size_t)(b * NH + h) * DK + d) * S_LEN + s0] = w;
            } else {
#pragma unroll
                for (int r = 0; r < 4; ++r) {
                    int gm = gm0 + r;
                    float val = (acc[m][n][r] + bias[gn]) * oscale;
                    if (OUT_MODE == 1) {
                        int b = gm >> 11, s = gm & 2047;
                        int h = gn >> 6, d = gn & 63;
                        ((unsigned short*)Cout)[((size_t)(b * NH + h) * S_LEN + s) * DK + d] = f2bf(val);
                    } else {
                        ((float*)Cout)[(size_t)gm * EMB_D + gn] = val;
                    }
                }
            }
        }
    }
}

// Flash attention, no-max-subtraction, P entirely in registers (round-6 proven, byte-exact).
__global__ __launch_bounds__(256, 4) void attn_fwd(
    const unsigned short* __restrict__ Qh, const unsigned short* __restrict__ Kh,
    const unsigned short* __restrict__ Vt, unsigned short* __restrict__ Aout)
{
    __shared__ unsigned short Ks[2][64][64];
    __shared__ unsigned short Vts[2][64][64];

    const int tid = threadIdx.x;
    const int lane = tid & 63;
    const int wid = tid >> 6;
    const int l15 = lane & 15, l4 = lane >> 4;
    const int lx7 = l15 & 7;

    const int bid = blockIdx.x;
    const int swz = (bid & 7) * 128 + (bid >> 3);
    const int bh = swz >> 4, qt = swz & 15;

    const unsigned short* Qb = Qh + (size_t)bh * S_LEN * DK;
    const unsigned short* Kb = Kh + (size_t)bh * S_LEN * DK;
    const unsigned short* Vtb = Vt + (size_t)bh * DK * S_LEN;

    const int srow = lane >> 3;
    const int sgl = lane & 7;

    auto stage = [&](int c, int kt) {
#pragma unroll
        for (int q2 = 0; q2 < 2; ++q2) {
            int q = wid * 2 + q2;
            int rho = q * 8 + srow;
            int kappa = ((rho >> 5) & 1) * 32 + ((rho >> 3) & 1) * 16 +
                        ((rho >> 2) & 1) * 8 + ((rho >> 4) & 1) * 4 + (rho & 3);
            gload16(&Kb[(size_t)(kt * 64 + kappa) * DK + (sgl ^ srow) * 8],
                    &Ks[c][q * 8][0]);
            gload16(&Vtb[(size_t)rho * S_LEN + kt * 64 + (sgl ^ srow) * 8],
                    &Vts[c][q * 8][0]);
        }
    };

    short8 qf[2][2];
#pragma unroll
    for (int m = 0; m < 2; ++m) {
        int qrow = qt * 128 + wid * 32 + m * 16 + l15;
#pragma unroll
        for (int h = 0; h < 2; ++h)
            qf[m][h] = *(const short8*)&Qb[(size_t)qrow * DK + h * 32 + l4 * 8];
    }

    f32x4 ot[2][5];
#pragma unroll
    for (int m = 0; m < 2; ++m)
#pragma unroll
        for (int n = 0; n < 5; ++n) {
            f32x4 z = {0.f, 0.f, 0.f, 0.f};
            ot[m][n] = z;
        }

    short8 ones;
#pragma unroll
    for (int e = 0; e < 8; ++e) ones[e] = (short)0x3F80;

    stage(0, 0);
    __syncthreads();

    for (int kt = 0; kt < S_LEN / 64; ++kt) {
        const int c = kt & 1;
        if (kt + 1 < S_LEN / 64) stage(c ^ 1, kt + 1);

        f32x4 st[2][4];
#pragma unroll
        for (int m = 0; m < 2; ++m)
#pragma unroll
            for (int kb = 0; kb < 4; ++kb) {
                f32x4 z = {0.f, 0.f, 0.f, 0.f};
                st[m][kb] = z;
            }
        __builtin_amdgcn_s_setprio(1);
#pragma unroll
        for (int h = 0; h < 2; ++h)
#pragma unroll
            for (int kb = 0; kb < 4; ++kb) {
                short8 kf = *(const short8*)&Ks[c][kb * 16 + l15][((h * 4 + l4) ^ lx7) * 8];
#pragma unroll
                for (int m = 0; m < 2; ++m)
                    st[m][kb] = __builtin_amdgcn_mfma_f32_16x16x32_bf16(kf, qf[m][h], st[m][kb], 0, 0, 0);
            }
        __builtin_amdgcn_s_setprio(0);

        short8 pa[2][2];
#pragma unroll
        for (int m = 0; m < 2; ++m) {
#pragma unroll
            for (int kb = 0; kb < 4; ++kb)
#pragma unroll
                for (int r = 0; r < 4; ++r)
                    st[m][kb][r] = __builtin_amdgcn_exp2f(st[m][kb][r]);
#pragma unroll
            for (int h = 0; h < 2; ++h) {
                uint4v w;
                w.x = cvtpk(st[m][2 * h][0], st[m][2 * h][1]);
                w.y = cvtpk(st[m][2 * h][2], st[m][2 * h][3]);
                w.z = cvtpk(st[m][2 * h + 1][0], st[m][2 * h + 1][1]);
                w.w = cvtpk(st[m][2 * h + 1][2], st[m][2 * h + 1][3]);
                pa[m][h] = __builtin_bit_cast(short8, w);
            }
        }

        __builtin_amdgcn_s_setprio(1);
#pragma unroll
        for (int n = 0; n < 4; ++n)
#pragma unroll
            for (int h = 0; h < 2; ++h) {
                short8 vb = *(const short8*)&Vts[c][n * 16 + l15][((h * 4 + l4) ^ lx7) * 8];
#pragma unroll
                for (int m = 0; m < 2; ++m)
                    ot[m][n] = __builtin_amdgcn_mfma_f32_16x16x32_bf16(pa[m][h], vb, ot[m][n], 0, 0, 0);
            }
#pragma unroll
        for (int h = 0; h < 2; ++h)
#pragma unroll
            for (int m = 0; m < 2; ++m)
                ot[m][4] = __builtin_amdgcn_mfma_f32_16x16x32_bf16(pa[m][h], ones, ot[m][4], 0, 0, 0);
        __builtin_amdgcn_s_setprio(0);
        __syncthreads();
    }

    const int b = bh >> 4, hh = bh & 15;
#pragma unroll
    for (int m = 0; m < 2; ++m) {
#pragma unroll
        for (int r = 0; r < 4; ++r) {
            float inv = 1.0f / ot[m][4][r];
            int s = qt * 128 + wid * 32 + m * 16 + l4 * 4 + r;
#pragma unroll
            for (int n = 0; n < 4; ++n) {
                int d = n * 16 + l15;
                Aout[((size_t)(b * S_LEN + s)) * EMB_D + hh * DK + d] = f2bf(ot[m][n][r] * inv);
            }
        }
    }
}

extern "C" void kernel_launch(void* const* d_in, const int* in_sizes, int n_in,
                              void* d_out, int out_size, void* d_ws, size_t ws_size,
                              hipStream_t stream) {
    const float* q  = (const float*)d_in[0];
    const float* k  = (const float*)d_in[1];
    const float* v  = (const float*)d_in[2];
    const float* Wq = (const float*)d_in[3];
    const float* bq = (const float*)d_in[4];
    const float* Wk = (const float*)d_in[5];
    const float* bk = (const float*)d_in[6];
    const float* Wv = (const float*)d_in[7];
    const float* bv = (const float*)d_in[8];
    const float* Wo = (const float*)d_in[9];
    const float* bo = (const float*)d_in[10];

    const size_t seg = (size_t)BATCH * NH * S_LEN * DK;  // 8,388,608
    const size_t wseg = (size_t)EMB_D * EMB_D;           // 1,048,576
    unsigned short* Qh = (unsigned short*)d_ws;
    unsigned short* Kh = Qh + seg;
    unsigned short* Vh = Kh + seg;    // V^T: [B*NH, DK, S]
    unsigned short* Ao = Vh + seg;    // [8192, 1024] bf16
    unsigned short* Wqb = Ao + seg;   // Wqb|Wkb|Wvb contiguous = Wcat
    unsigned short* Wkb = Wqb + wseg;
    unsigned short* Wvb = Wkb + wseg;
    unsigned short* Wob = Wvb + wseg;
    unsigned short* qb = Wob + wseg;
    unsigned short* kb2 = qb + seg;
    unsigned short* vb2 = kb2 + seg;

    const size_t full_elems = seg * 7 + wseg * 4;
    const bool full = ws_size >= full_elems * 2;

    const float qscale = 0.18033688011112042f;  // (1/sqrt(64)) * log2(e)

    const int WBLK = (int)(wseg / 2048);  // 512
    const int SBLK = (int)(seg / 2048);   // 4096

    CvtArgs ca;
    ca.src[0] = Wq;  ca.dst[0] = Wqb;
    ca.src[1] = Wk;  ca.dst[1] = Wkb;
    ca.src[2] = Wv;  ca.dst[2] = Wvb;
    ca.src[3] = Wo;  ca.dst[3] = Wob;
    ca.starts[0] = 0;
    ca.starts[1] = WBLK;
    ca.starts[2] = WBLK * 2;
    ca.starts[3] = WBLK * 3;
    int nb = WBLK * 4;
    if (full) {
        ca.src[4] = q; ca.dst[4] = qb;
        ca.src[5] = k; ca.dst[5] = kb2;
        ca.src[6] = v; ca.dst[6] = vb2;
        ca.starts[4] = nb;
        ca.starts[5] = nb + SBLK;
        ca.starts[6] = nb + SBLK * 2;
        ca.ntens = 7;
        nb += SBLK * 3;
    } else {
        ca.src[4] = ca.src[5] = ca.src[6] = Wq;
        ca.dst[4] = ca.dst[5] = ca.dst[6] = Wqb;
        ca.starts[4] = ca.starts[5] = ca.starts[6] = nb;
        ca.ntens = 4;
    }
    ca.starts[7] = nb;
    cvt_all<<<nb, 256, 0, stream>>>(ca);

    if (full) {
        gemm_qkv32<<<1536, 256, 0, stream>>>(qb, kb2, vb2, Wqb, bq, bk, bv,
                                             Qh, Kh, Vh, qscale);
    } else {
        gemm_bt<0, 1><<<512, 256, 0, stream>>>((const void*)q, Wqb, bq, (void*)Qh, qscale);
        gemm_bt<0, 1><<<512, 256, 0, stream>>>((const void*)k, Wkb, bk, (void*)Kh, 1.0f);
        gemm_bt<0, 2><<<512, 256, 0, stream>>>((const void*)v, Wvb, bv, (void*)Vh, 1.0f);
    }

    attn_fwd<<<1024, 256, 0, stream>>>(Qh, Kh, Vh, Ao);

    gemm32_f32out<<<512, 256, 0, stream>>>(Ao, Wob, bo, (float*)d_out);
}

// Round 10
// 177.904 us; speedup vs baseline: 1.1559x; 1.1559x over previous
//
#include <hip/hip_runtime.h>
#include <hip/hip_bf16.h>

#define S_LEN 2048
#define EMB_D 1024
#define NH 16
#define DK 64
#define BATCH 4

typedef __attribute__((ext_vector_type(8))) short short8;
typedef __attribute__((ext_vector_type(4))) float f32x4;
typedef __attribute__((ext_vector_type(8))) unsigned short ushort8;
typedef __attribute__((ext_vector_type(4))) unsigned short ushort4v;
typedef __attribute__((ext_vector_type(4))) unsigned int uint4v;
typedef __attribute__((ext_vector_type(2))) unsigned int uint2v;

__device__ inline unsigned short f2bf(float x) {
    unsigned u = __builtin_bit_cast(unsigned, x);
    u = (u + 0x7fffu + ((u >> 16) & 1u)) >> 16;
    return (unsigned short)u;
}

__device__ inline unsigned cvtpk(float lo, float hi) {
    unsigned r;
    asm("v_cvt_pk_bf16_f32 %0, %1, %2" : "=v"(r) : "v"(lo), "v"(hi));
    return r;
}

typedef const __attribute__((address_space(1))) unsigned int* gas_p;
typedef __attribute__((address_space(3))) unsigned int* las_p;
__device__ inline void gload16(const void* g, void* l) {
    __builtin_amdgcn_global_load_lds((gas_p)g, (las_p)l, 16, 0, 0);
}

// ---- fused f32 -> bf16 conversion over up to 7 tensors ----
struct CvtArgs {
    const float* src[7];
    unsigned short* dst[7];
    int starts[8];
    int ntens;
};

__global__ __launch_bounds__(256) void cvt_all(CvtArgs a) {
    int b = blockIdx.x;
    int t = 0;
#pragma unroll
    for (int i = 1; i < 7; ++i)
        if (i < a.ntens && b >= a.starts[i]) t = i;
    int rel = b - a.starts[t];
    size_t i = (size_t)rel * 2048 + (size_t)threadIdx.x * 8;
    float4 x = *(const float4*)&a.src[t][i];
    float4 y = *(const float4*)&a.src[t][i + 4];
    uint4v w;
    w.x = cvtpk(x.x, x.y); w.y = cvtpk(x.z, x.w);
    w.z = cvtpk(y.x, y.y); w.w = cvtpk(y.z, y.w);
    *(uint4v*)&a.dst[t][i] = w;
}

// ---- fused QKV projection: single-buffered BK=64 (m97-style), 32 KB LDS, 4 blocks/CU ----
// bid -> xcd = bid&7, j = bid>>3; tau = j>>6 (q/k/v); jj = j&63; bnl = jj&7; bm = xcd*8 + (jj>>3).
__global__ __launch_bounds__(256, 4) void gemm_qkv(
    const unsigned short* __restrict__ Aq, const unsigned short* __restrict__ Ak,
    const unsigned short* __restrict__ Av, const unsigned short* __restrict__ Wcat,
    const float* __restrict__ bq, const float* __restrict__ bk, const float* __restrict__ bv,
    unsigned short* __restrict__ Qh, unsigned short* __restrict__ Kh,
    unsigned short* __restrict__ Vt, float qscale)
{
    const int K = EMB_D;
    __shared__ unsigned short As[128][64];   // 16 KB
    __shared__ unsigned short Bs[128][64];   // 16 KB

    const int tid = threadIdx.x;
    const int lane = tid & 63;
    const int wid = tid >> 6;
    const int wr = wid >> 1, wc = wid & 1;
    const int l15 = lane & 15, l4 = lane >> 4;
    const int lx7 = l15 & 7;

    const int bid = blockIdx.x;
    const int xcd = bid & 7, j = bid >> 3;
    const int tau = j >> 6, jj = j & 63;
    const int bnl = jj & 7;
    const int bm = xcd * 8 + (jj >> 3);

    const unsigned short* Ab = tau == 0 ? Aq : (tau == 1 ? Ak : Av);
    const unsigned short* Bw = Wcat + (size_t)tau * (size_t)EMB_D * EMB_D;
    const float* bias = tau == 0 ? bq : (tau == 1 ? bk : bv);
    const float osc = tau == 0 ? qscale : 1.0f;

    const int srow = lane >> 3;
    const int sgl = lane & 7;

    f32x4 acc[4][4];
#pragma unroll
    for (int m = 0; m < 4; ++m)
#pragma unroll
        for (int n = 0; n < 4; ++n) {
            f32x4 z = {0.f, 0.f, 0.f, 0.f};
            acc[m][n] = z;
        }

    for (int kt = 0; kt < K / 64; ++kt) {
#pragma unroll
        for (int q2 = 0; q2 < 4; ++q2) {
            int r = wid * 32 + q2 * 8 + srow;
            gload16(&Ab[(size_t)(bm * 128 + r) * K + kt * 64 + (sgl ^ srow) * 8],
                    &As[wid * 32 + q2 * 8][0]);
        }
#pragma unroll
        for (int q2 = 0; q2 < 4; ++q2) {
            int r = wid * 32 + q2 * 8 + srow;
            gload16(&Bw[(size_t)(bnl * 128 + r) * K + kt * 64 + (sgl ^ srow) * 8],
                    &Bs[wid * 32 + q2 * 8][0]);
        }
        __syncthreads();   // drains gload_lds (vmcnt) -> tiles ready
#pragma unroll
        for (int h = 0; h < 2; ++h) {
            short8 af[4], bf[4];
#pragma unroll
            for (int m = 0; m < 4; ++m)
                af[m] = *(const short8*)&As[wr * 64 + m * 16 + l15][((h * 4 + l4) ^ lx7) * 8];
#pragma unroll
            for (int n = 0; n < 4; ++n)
                bf[n] = *(const short8*)&Bs[wc * 64 + n * 16 + l15][((h * 4 + l4) ^ lx7) * 8];
#pragma unroll
            for (int m = 0; m < 4; ++m)
#pragma unroll
                for (int n = 0; n < 4; ++n)
                    acc[m][n] = __builtin_amdgcn_mfma_f32_16x16x32_bf16(af[m], bf[n], acc[m][n], 0, 0, 0);
        }
        __syncthreads();   // all reads done before next-iter staging overwrites
    }

#pragma unroll
    for (int m = 0; m < 4; ++m) {
#pragma unroll
        for (int n = 0; n < 4; ++n) {
            int gm0 = bm * 128 + wr * 64 + m * 16 + l4 * 4;
            int gn = bnl * 128 + wc * 64 + n * 16 + l15;
            if (tau == 2) {
                int b = gm0 >> 11, s0 = gm0 & 2047;
                int h = gn >> 6, d = gn & 63;
                ushort4v w;
#pragma unroll
                for (int r = 0; r < 4; ++r)
                    w[r] = f2bf(acc[m][n][r] + bias[gn]);
                *(ushort4v*)&Vt[((size_t)(b * NH + h) * DK + d) * S_LEN + s0] = w;
            } else {
                unsigned short* Out = tau == 0 ? Qh : Kh;
#pragma unroll
                for (int r = 0; r < 4; ++r) {
                    int gm = gm0 + r;
                    float val = (acc[m][n][r] + bias[gn]) * osc;
                    int b = gm >> 11, s = gm & 2047;
                    int h = gn >> 6, d = gn & 63;
                    Out[((size_t)(b * NH + h) * S_LEN + s) * DK + d] = f2bf(val);
                }
            }
        }
    }
}

// ---- final output projection: single-buffered BK=64, A bf16 @ W^T + bias -> f32 ----
__global__ __launch_bounds__(256, 4) void gemm_o(
    const unsigned short* __restrict__ Ain, const unsigned short* __restrict__ Bw,
    const float* __restrict__ bias, float* __restrict__ Cout)
{
    const int K = EMB_D;
    __shared__ unsigned short As[128][64];
    __shared__ unsigned short Bs[128][64];

    const int tid = threadIdx.x;
    const int lane = tid & 63;
    const int wid = tid >> 6;
    const int wr = wid >> 1, wc = wid & 1;
    const int l15 = lane & 15, l4 = lane >> 4;
    const int lx7 = l15 & 7;

    const int bid = blockIdx.x;
    const int bm = (bid & 7) * 8 + (bid >> 6);
    const int bn = (bid >> 3) & 7;

    const int srow = lane >> 3;
    const int sgl = lane & 7;

    f32x4 acc[4][4];
#pragma unroll
    for (int m = 0; m < 4; ++m)
#pragma unroll
        for (int n = 0; n < 4; ++n) {
            f32x4 z = {0.f, 0.f, 0.f, 0.f};
            acc[m][n] = z;
        }

    for (int kt = 0; kt < K / 64; ++kt) {
#pragma unroll
        for (int q2 = 0; q2 < 4; ++q2) {
            int r = wid * 32 + q2 * 8 + srow;
            gload16(&Ain[(size_t)(bm * 128 + r) * K + kt * 64 + (sgl ^ srow) * 8],
                    &As[wid * 32 + q2 * 8][0]);
        }
#pragma unroll
        for (int q2 = 0; q2 < 4; ++q2) {
            int r = wid * 32 + q2 * 8 + srow;
            gload16(&Bw[(size_t)(bn * 128 + r) * K + kt * 64 + (sgl ^ srow) * 8],
                    &Bs[wid * 32 + q2 * 8][0]);
        }
        __syncthreads();
#pragma unroll
        for (int h = 0; h < 2; ++h) {
            short8 af[4], bf[4];
#pragma unroll
            for (int m = 0; m < 4; ++m)
                af[m] = *(const short8*)&As[wr * 64 + m * 16 + l15][((h * 4 + l4) ^ lx7) * 8];
#pragma unroll
            for (int n = 0; n < 4; ++n)
                bf[n] = *(const short8*)&Bs[wc * 64 + n * 16 + l15][((h * 4 + l4) ^ lx7) * 8];
#pragma unroll
            for (int m = 0; m < 4; ++m)
#pragma unroll
                for (int n = 0; n < 4; ++n)
                    acc[m][n] = __builtin_amdgcn_mfma_f32_16x16x32_bf16(af[m], bf[n], acc[m][n], 0, 0, 0);
        }
        __syncthreads();
    }

#pragma unroll
    for (int m = 0; m < 4; ++m) {
#pragma unroll
        for (int n = 0; n < 4; ++n) {
            int gm0 = bm * 128 + wr * 64 + m * 16 + l4 * 4;
            int gn = bn * 128 + wc * 64 + n * 16 + l15;
#pragma unroll
            for (int r = 0; r < 4; ++r)
                Cout[(size_t)(gm0 + r) * EMB_D + gn] = acc[m][n][r] + bias[gn];
        }
    }
}

// ---- legacy BK=64 dbuf GEMM (fallback path only, round-8 proven) ----
template<int A_MODE, int OUT_MODE>
__global__ __launch_bounds__(256) void gemm_bt(
    const void* __restrict__ Aptr, const unsigned short* __restrict__ Bw,
    const float* __restrict__ bias, void* __restrict__ Cout, float oscale)
{
    const int K = EMB_D;
    __shared__ unsigned short As[2][128][64];
    __shared__ unsigned short Bs[2][128][64];

    const int tid = threadIdx.x;
    const int lane = tid & 63;
    const int wid = tid >> 6;
    const int wr = wid >> 1, wc = wid & 1;
    const int l15 = lane & 15, l4 = lane >> 4;
    const int lx7 = l15 & 7;

    const int bid = blockIdx.x;
    const int bm = (bid & 7) * 8 + (bid >> 6);
    const int bn = (bid >> 3) & 7;

    const int srow = lane >> 3;
    const int sgl = lane & 7;

    const float* Af = (const float*)Aptr;
    const unsigned short* Ab = (const unsigned short*)Aptr;

    f32x4 acc[4][4];
#pragma unroll
    for (int m = 0; m < 4; ++m)
#pragma unroll
        for (int n = 0; n < 4; ++n) {
            f32x4 z = {0.f, 0.f, 0.f, 0.f};
            acc[m][n] = z;
        }

    float4 areg[8];

    auto stageB = [&](int c, int kt) {
#pragma unroll
        for (int q2 = 0; q2 < 4; ++q2) {
            int r = wid * 32 + q2 * 8 + srow;
            gload16(&Bw[(size_t)(bn * 128 + r) * K + kt * 64 + (sgl ^ srow) * 8],
                    &Bs[c][wid * 32 + q2 * 8][0]);
        }
    };
    auto stageA1 = [&](int c, int kt) {
#pragma unroll
        for (int q2 = 0; q2 < 4; ++q2) {
            int r = wid * 32 + q2 * 8 + srow;
            gload16(&Ab[(size_t)(bm * 128 + r) * K + kt * 64 + (sgl ^ srow) * 8],
                    &As[c][wid * 32 + q2 * 8][0]);
        }
    };
    auto loadA0 = [&](int kt) {
#pragma unroll
        for (int j = 0; j < 8; ++j) {
            int f = tid + j * 256;
            int r = f >> 4, c4 = f & 15;
            areg[j] = *(const float4*)&Af[(size_t)(bm * 128 + r) * K + kt * 64 + c4 * 4];
        }
    };
    auto writeA0 = [&](int c) {
#pragma unroll
        for (int j = 0; j < 8; ++j) {
            int f = tid + j * 256;
            int r = f >> 4, c4 = f & 15;
            uint2v w;
            w.x = cvtpk(areg[j].x, areg[j].y);
            w.y = cvtpk(areg[j].z, areg[j].w);
            int col = (((c4 >> 1) ^ (r & 7)) << 3) + ((c4 & 1) << 2);
            *(uint2v*)&As[c][r][col] = w;
        }
    };

    if (A_MODE == 0) loadA0(0); else stageA1(0, 0);
    stageB(0, 0);
    if (A_MODE == 0) {
        asm volatile("s_waitcnt vmcnt(0)" ::: "memory");
        writeA0(0);
    }
    __syncthreads();

    for (int kt = 0; kt < K / 64; ++kt) {
        const int c = kt & 1;
        const bool pf = (kt + 1 < K / 64);
        if (pf) {
            if (A_MODE == 0) loadA0(kt + 1); else stageA1(c ^ 1, kt + 1);
            stageB(c ^ 1, kt + 1);
        }
#pragma unroll
        for (int h = 0; h < 2; ++h) {
            short8 af[4], bf[4];
#pragma unroll
            for (int m = 0; m < 4; ++m)
                af[m] = *(const short8*)&As[c][wr * 64 + m * 16 + l15][((h * 4 + l4) ^ lx7) * 8];
#pragma unroll
            for (int n = 0; n < 4; ++n)
                bf[n] = *(const short8*)&Bs[c][wc * 64 + n * 16 + l15][((h * 4 + l4) ^ lx7) * 8];
#pragma unroll
            for (int m = 0; m < 4; ++m)
#pragma unroll
                for (int n = 0; n < 4; ++n)
                    acc[m][n] = __builtin_amdgcn_mfma_f32_16x16x32_bf16(af[m], bf[n], acc[m][n], 0, 0, 0);
        }
        if (pf && A_MODE == 0) {
            asm volatile("s_waitcnt vmcnt(0)" ::: "memory");
            writeA0(c ^ 1);
        }
        __syncthreads();
    }

#pragma unroll
    for (int m = 0; m < 4; ++m) {
#pragma unroll
        for (int n = 0; n < 4; ++n) {
            int gm0 = bm * 128 + wr * 64 + m * 16 + l4 * 4;
            int gn = bn * 128 + wc * 64 + n * 16 + l15;
            if (OUT_MODE == 2) {
                int b = gm0 >> 11, s0 = gm0 & 2047;
                int h = gn >> 6, d = gn & 63;
                ushort4v w;
#pragma unroll
                for (int r = 0; r < 4; ++r)
                    w[r] = f2bf((acc[m][n][r] + bias[gn]) * oscale);
                *(ushort4v*)&((unsigned short*)Cout)[((size_t)(b * NH + h) * DK + d) * S_LEN + s0] = w;
            } else {
#pragma unroll
                for (int r = 0; r < 4; ++r) {
                    int gm = gm0 + r;
                    float val = (acc[m][n][r] + bias[gn]) * oscale;
                    if (OUT_MODE == 1) {
                        int b = gm >> 11, s = gm & 2047;
                        int h = gn >> 6, d = gn & 63;
                        ((unsigned short*)Cout)[((size_t)(b * NH + h) * S_LEN + s) * DK + d] = f2bf(val);
                    } else {
                        ((float*)Cout)[(size_t)gm * EMB_D + gn] = val;
                    }
                }
            }
        }
    }
}

// Flash attention, no-max-subtraction, P entirely in registers (round-6 proven, byte-exact).
__global__ __launch_bounds__(256, 4) void attn_fwd(
    const unsigned short* __restrict__ Qh, const unsigned short* __restrict__ Kh,
    const unsigned short* __restrict__ Vt, unsigned short* __restrict__ Aout)
{
    __shared__ unsigned short Ks[2][64][64];
    __shared__ unsigned short Vts[2][64][64];

    const int tid = threadIdx.x;
    const int lane = tid & 63;
    const int wid = tid >> 6;
    const int l15 = lane & 15, l4 = lane >> 4;
    const int lx7 = l15 & 7;

    const int bid = blockIdx.x;
    const int swz = (bid & 7) * 128 + (bid >> 3);
    const int bh = swz >> 4, qt = swz & 15;

    const unsigned short* Qb = Qh + (size_t)bh * S_LEN * DK;
    const unsigned short* Kb = Kh + (size_t)bh * S_LEN * DK;
    const unsigned short* Vtb = Vt + (size_t)bh * DK * S_LEN;

    const int srow = lane >> 3;
    const int sgl = lane & 7;

    auto stage = [&](int c, int kt) {
#pragma unroll
        for (int q2 = 0; q2 < 2; ++q2) {
            int q = wid * 2 + q2;
            int rho = q * 8 + srow;
            int kappa = ((rho >> 5) & 1) * 32 + ((rho >> 3) & 1) * 16 +
                        ((rho >> 2) & 1) * 8 + ((rho >> 4) & 1) * 4 + (rho & 3);
            gload16(&Kb[(size_t)(kt * 64 + kappa) * DK + (sgl ^ srow) * 8],
                    &Ks[c][q * 8][0]);
            gload16(&Vtb[(size_t)rho * S_LEN + kt * 64 + (sgl ^ srow) * 8],
                    &Vts[c][q * 8][0]);
        }
    };

    short8 qf[2][2];
#pragma unroll
    for (int m = 0; m < 2; ++m) {
        int qrow = qt * 128 + wid * 32 + m * 16 + l15;
#pragma unroll
        for (int h = 0; h < 2; ++h)
            qf[m][h] = *(const short8*)&Qb[(size_t)qrow * DK + h * 32 + l4 * 8];
    }

    f32x4 ot[2][5];
#pragma unroll
    for (int m = 0; m < 2; ++m)
#pragma unroll
        for (int n = 0; n < 5; ++n) {
            f32x4 z = {0.f, 0.f, 0.f, 0.f};
            ot[m][n] = z;
        }

    short8 ones;
#pragma unroll
    for (int e = 0; e < 8; ++e) ones[e] = (short)0x3F80;

    stage(0, 0);
    __syncthreads();

    for (int kt = 0; kt < S_LEN / 64; ++kt) {
        const int c = kt & 1;
        if (kt + 1 < S_LEN / 64) stage(c ^ 1, kt + 1);

        f32x4 st[2][4];
#pragma unroll
        for (int m = 0; m < 2; ++m)
#pragma unroll
            for (int kb = 0; kb < 4; ++kb) {
                f32x4 z = {0.f, 0.f, 0.f, 0.f};
                st[m][kb] = z;
            }
        __builtin_amdgcn_s_setprio(1);
#pragma unroll
        for (int h = 0; h < 2; ++h)
#pragma unroll
            for (int kb = 0; kb < 4; ++kb) {
                short8 kf = *(const short8*)&Ks[c][kb * 16 + l15][((h * 4 + l4) ^ lx7) * 8];
#pragma unroll
                for (int m = 0; m < 2; ++m)
                    st[m][kb] = __builtin_amdgcn_mfma_f32_16x16x32_bf16(kf, qf[m][h], st[m][kb], 0, 0, 0);
            }
        __builtin_amdgcn_s_setprio(0);

        short8 pa[2][2];
#pragma unroll
        for (int m = 0; m < 2; ++m) {
#pragma unroll
            for (int kb = 0; kb < 4; ++kb)
#pragma unroll
                for (int r = 0; r < 4; ++r)
                    st[m][kb][r] = __builtin_amdgcn_exp2f(st[m][kb][r]);
#pragma unroll
            for (int h = 0; h < 2; ++h) {
                uint4v w;
                w.x = cvtpk(st[m][2 * h][0], st[m][2 * h][1]);
                w.y = cvtpk(st[m][2 * h][2], st[m][2 * h][3]);
                w.z = cvtpk(st[m][2 * h + 1][0], st[m][2 * h + 1][1]);
                w.w = cvtpk(st[m][2 * h + 1][2], st[m][2 * h + 1][3]);
                pa[m][h] = __builtin_bit_cast(short8, w);
            }
        }

        __builtin_amdgcn_s_setprio(1);
#pragma unroll
        for (int n = 0; n < 4; ++n)
#pragma unroll
            for (int h = 0; h < 2; ++h) {
                short8 vb = *(const short8*)&Vts[c][n * 16 + l15][((h * 4 + l4) ^ lx7) * 8];
#pragma unroll
                for (int m = 0; m < 2; ++m)
                    ot[m][n] = __builtin_amdgcn_mfma_f32_16x16x32_bf16(pa[m][h], vb, ot[m][n], 0, 0, 0);
            }
#pragma unroll
        for (int h = 0; h < 2; ++h)
#pragma unroll
            for (int m = 0; m < 2; ++m)
                ot[m][4] = __builtin_amdgcn_mfma_f32_16x16x32_bf16(pa[m][h], ones, ot[m][4], 0, 0, 0);
        __builtin_amdgcn_s_setprio(0);
        __syncthreads();
    }

    const int b = bh >> 4, hh = bh & 15;
#pragma unroll
    for (int m = 0; m < 2; ++m) {
#pragma unroll
        for (int r = 0; r < 4; ++r) {
            float inv = 1.0f / ot[m][4][r];
            int s = qt * 128 + wid * 32 + m * 16 + l4 * 4 + r;
#pragma unroll
            for (int n = 0; n < 4; ++n) {
                int d = n * 16 + l15;
                Aout[((size_t)(b * S_LEN + s)) * EMB_D + hh * DK + d] = f2bf(ot[m][n][r] * inv);
            }
        }
    }
}

extern "C" void kernel_launch(void* const* d_in, const int* in_sizes, int n_in,
                              void* d_out, int out_size, void* d_ws, size_t ws_size,
                              hipStream_t stream) {
    const float* q  = (const float*)d_in[0];
    const float* k  = (const float*)d_in[1];
    const float* v  = (const float*)d_in[2];
    const float* Wq = (const float*)d_in[3];
    const float* bq = (const float*)d_in[4];
    const float* Wk = (const float*)d_in[5];
    const float* bk = (const float*)d_in[6];
    const float* Wv = (const float*)d_in[7];
    const float* bv = (const float*)d_in[8];
    const float* Wo = (const float*)d_in[9];
    const float* bo = (const float*)d_in[10];

    const size_t seg = (size_t)BATCH * NH * S_LEN * DK;  // 8,388,608
    const size_t wseg = (size_t)EMB_D * EMB_D;           // 1,048,576
    unsigned short* Qh = (unsigned short*)d_ws;
    unsigned short* Kh = Qh + seg;
    unsigned short* Vh = Kh + seg;    // V^T: [B*NH, DK, S]
    unsigned short* Ao = Vh + seg;    // [8192, 1024] bf16
    unsigned short* Wqb = Ao + seg;   // Wqb|Wkb|Wvb contiguous = Wcat
    unsigned short* Wkb = Wqb + wseg;
    unsigned short* Wvb = Wkb + wseg;
    unsigned short* Wob = Wvb + wseg;
    unsigned short* qb = Wob + wseg;
    unsigned short* kb2 = qb + seg;
    unsigned short* vb2 = kb2 + seg;

    const size_t full_elems = seg * 7 + wseg * 4;
    const bool full = ws_size >= full_elems * 2;

    const float qscale = 0.18033688011112042f;  // (1/sqrt(64)) * log2(e)

    const int WBLK = (int)(wseg / 2048);  // 512
    const int SBLK = (int)(seg / 2048);   // 4096

    CvtArgs ca;
    ca.src[0] = Wq;  ca.dst[0] = Wqb;
    ca.src[1] = Wk;  ca.dst[1] = Wkb;
    ca.src[2] = Wv;  ca.dst[2] = Wvb;
    ca.src[3] = Wo;  ca.dst[3] = Wob;
    ca.starts[0] = 0;
    ca.starts[1] = WBLK;
    ca.starts[2] = WBLK * 2;
    ca.starts[3] = WBLK * 3;
    int nb = WBLK * 4;
    if (full) {
        ca.src[4] = q; ca.dst[4] = qb;
        ca.src[5] = k; ca.dst[5] = kb2;
        ca.src[6] = v; ca.dst[6] = vb2;
        ca.starts[4] = nb;
        ca.starts[5] = nb + SBLK;
        ca.starts[6] = nb + SBLK * 2;
        ca.ntens = 7;
        nb += SBLK * 3;
    } else {
        ca.src[4] = ca.src[5] = ca.src[6] = Wq;
        ca.dst[4] = ca.dst[5] = ca.dst[6] = Wqb;
        ca.starts[4] = ca.starts[5] = ca.starts[6] = nb;
        ca.ntens = 4;
    }
    ca.starts[7] = nb;
    cvt_all<<<nb, 256, 0, stream>>>(ca);

    if (full) {
        gemm_qkv<<<1536, 256, 0, stream>>>(qb, kb2, vb2, Wqb, bq, bk, bv,
                                           Qh, Kh, Vh, qscale);
    } else {
        gemm_bt<0, 1><<<512, 256, 0, stream>>>((const void*)q, Wqb, bq, (void*)Qh, qscale);
        gemm_bt<0, 1><<<512, 256, 0, stream>>>((const void*)k, Wkb, bk, (void*)Kh, 1.0f);
        gemm_bt<0, 2><<<512, 256, 0, stream>>>((const void*)v, Wvb, bv, (void*)Vh, 1.0f);
    }

    attn_fwd<<<1024, 256, 0, stream>>>(Qh, Kh, Vh, Ao);

    gemm_o<<<512, 256, 0, stream>>>(Ao, Wob, bo, (float*)d_out);
}